// Round 5
// baseline (905.617 us; speedup 1.0000x reference)
//
#include <hip/hip_runtime.h>

static constexpr int T_LEN = 1024;

typedef float f32x2 __attribute__((ext_vector_type(2)));

__device__ __forceinline__ f32x2 fma2(f32x2 a, f32x2 b, f32x2 c) {
#if __has_builtin(__builtin_elementwise_fma)
    return __builtin_elementwise_fma(a, b, c);
#else
    f32x2 d; d.x = fmaf(a.x, b.x, c.x); d.y = fmaf(a.y, b.y, c.y); return d;
#endif
}
// 1/(1+2^t): overflow-safe (t->+inf: exp2=inf, rcp->0; t->-inf: ->1)
__device__ __forceinline__ float sig2(float t) {
    return __builtin_amdgcn_rcpf(1.f + __builtin_amdgcn_exp2f(t));
}
__device__ __forceinline__ float bperm(int addr, float v) {
    return __int_as_float(__builtin_amdgcn_ds_bpermute(addr, __float_as_int(v)));
}

// DPP row_ror:Q within 16-lane rows (full-rate VALU cross-lane; h is
// replicated per row, so rotation == broadcast traversal of all h[k]).
template <int Q>
__device__ __forceinline__ float rorq(float v) {
    if constexpr ((Q & 15) == 0) {
        return v;
    } else {
        return __uint_as_float((unsigned)__builtin_amdgcn_update_dpp(
            0, (int)__float_as_uint(v), 0x120 + (Q & 15), 0xF, 0xF, false));
    }
}

// Layer-1: 8 paired steps (k-slots q and q+8) accumulating A (layer-1 gates)
// and X (layer-2 input projection) as f32x2 -> v_pk_fma_f32.
template <int Q>
struct L1Step {
    static __device__ __forceinline__ void run(
        float h, float hb, const f32x2 (&w0p)[8], const f32x2 (&wxp)[8],
        f32x2& A2, f32x2& X2) {
        f32x2 hp;
        hp.x = rorq<Q>(h);
        hp.y = rorq<Q>(hb);
        A2 = fma2(w0p[Q], hp, A2);
        X2 = fma2(wxp[Q], hp, X2);
        L1Step<Q + 1>::run(h, hb, w0p, wxp, A2, X2);
    }
};
template <>
struct L1Step<8> {
    static __device__ __forceinline__ void run(
        float, float, const f32x2 (&)[8], const f32x2 (&)[8], f32x2&, f32x2&) {}
};

// X-only paired chain (epilogue step T-1 projection).
template <int Q>
struct XStep {
    static __device__ __forceinline__ void run(
        float h, float hb, const f32x2 (&wxp)[8], f32x2& X2) {
        f32x2 hp;
        hp.x = rorq<Q>(h);
        hp.y = rorq<Q>(hb);
        X2 = fma2(wxp[Q], hp, X2);
        XStep<Q + 1>::run(h, hb, wxp, X2);
    }
};
template <>
struct XStep<8> {
    static __device__ __forceinline__ void run(float, float, const f32x2 (&)[8], f32x2&) {}
};

// Scalar 16-step chain: B += w[q]*ror_q(h). Single-use dpp -> folds to
// v_fmac_f32 with dpp (1 instr per term).
template <int Q>
struct ChainStep {
    static __device__ __forceinline__ void run(float h, const float (&w)[16], float& B) {
        B = fmaf(w[Q], rorq<Q>(h), B);
        ChainStep<Q + 1>::run(h, w, B);
    }
};
template <>
struct ChainStep<16> {
    static __device__ __forceinline__ void run(float, const float (&)[16], float&) {}
};

// One wave per batch element. Lane r owns gate row r (PyTorch i,f,g,o).
// Weights are stored PRE-ROTATED per lane (slot q holds W[r][(j+delta*q)&15],
// delta probed from the hardware DPP rotate direction at init) and PRE-SCALED
// by the row's -log2e activation factor. h broadcasts ride DPP row_ror; only
// the 4-gate gathers use ds_bpermute. Layer 2 runs two steps delayed via Xp.
__global__ void __launch_bounds__(256)
__attribute__((amdgpu_waves_per_eu(4, 4)))
lstm2_dpp_kernel(
    const float* __restrict__ x,
    const float* __restrict__ Wih0, const float* __restrict__ Whh0,
    const float* __restrict__ bih0, const float* __restrict__ bhh0,
    const float* __restrict__ Wih1, const float* __restrict__ Whh1,
    const float* __restrict__ bih1, const float* __restrict__ bhh1,
    const float* __restrict__ Wout, const float* __restrict__ bout,
    float* __restrict__ out)
{
    const int tid  = threadIdx.x;
    const int lane = tid & 63;
    const int j    = lane & 15;
    const int gi   = lane >> 4;
    const int b    = blockIdx.x * 4 + (tid >> 6);

    // Probe DPP row_ror:1 direction with the lane index (self-calibrating).
    const int got = __builtin_amdgcn_update_dpp(0, j, 0x121, 0xF, 0xF, false);
    const int delta = (got - j) & 15;

    // activation constants: gate group 2 (rows 32..47) uses tanh = 2*sig(2v)-1
    const bool  isg  = (gi == 2);
    const float nsc  = isg ? -2.885390082f : -1.442695041f;  // -scale*log2e
    const float amul = isg ? 2.f : 1.f;
    const float aadd = isg ? -1.f : 0.f;
    const float NT   = -2.885390082f;

    // ---- pre-rotated, pre-scaled per-lane weights, then PIN them.
    f32x2 w0p[8], wxp[8];
    float w1rot[16];
#pragma unroll
    for (int q = 0; q < 8; ++q) {
        const int mA = (j + delta * q) & 15;
        const int mB = (j + delta * (q + 8)) & 15;
        w0p[q] = (f32x2){nsc * Whh0[lane * 16 + mA], nsc * Whh0[lane * 16 + mB]};
        wxp[q] = (f32x2){nsc * Wih1[lane * 16 + mA], nsc * Wih1[lane * 16 + mB]};
    }
#pragma unroll
    for (int q = 0; q < 16; ++q)
        w1rot[q] = nsc * Whh1[lane * 16 + ((j + delta * q) & 15)];
    float wi0s = nsc * Wih0[lane];
    float bb0s = nsc * (bih0[lane] + bhh0[lane]);
    float bb1s = nsc * (bih1[lane] + bhh1[lane]);
#pragma unroll
    for (int q = 0; q < 8; ++q)
        asm volatile("" : "+v"(w0p[q]), "+v"(wxp[q]), "+v"(w1rot[2*q]), "+v"(w1rot[2*q+1]));
    asm volatile("" : "+v"(wi0s), "+v"(bb0s), "+v"(bb1s));

    // opaque zero VGPR: gather lane indices fold into the DS offset field.
    int zero;
    asm volatile("v_mov_b32 %0, 0" : "=v"(zero));
    const int aj = zero + (j << 2);

    float h1 = 0.f, c1 = 0.f, h2 = 0.f, c2 = 0.f, Xp = 0.f;
    float hb1 = 0.f;   // ror<8>(h1), maintained each step for the paired chain

    const float* xb = x + (size_t)b * T_LEN;
    float4 xq = *reinterpret_cast<const float4*>(xb);

    for (int tb = 0; tb < T_LEN; tb += 4) {
        float4 xn = xq;
        if (tb + 4 < T_LEN)
            xn = *reinterpret_cast<const float4*>(xb + tb + 4);
#pragma unroll
        for (int u = 0; u < 4; ++u) {
            const int   t  = tb + u;
            const float xt = (u==0)?xq.x:(u==1)?xq.y:(u==2)?xq.z:xq.w;

            // (1) layer-1 paired chain: A (gates, scaled) + X (projection, scaled)
            f32x2 A2 = {fmaf(wi0s, xt, bb0s), 0.f};
            f32x2 X2 = {bb1s, 0.f};
            L1Step<0>::run(h1, hb1, w0p, wxp, A2, X2);
            const float A = A2.x + A2.y;
            const float X = X2.x + X2.y;

            // (2) layer-1 act; issue its gathers early (latency hides under L2)
            const float act1 = fmaf(amul, sig2(A), aadd);
            const float i1 = bperm(aj,       act1);
            const float f1 = bperm(aj +  64, act1);
            const float g1 = bperm(aj + 128, act1);
            const float o1 = bperm(aj + 192, act1);

            // (3) layer-2 step t-2 (independent chain; dpp folds into fmac)
            if (t >= 2) {
                float B = Xp;
                ChainStep<0>::run(h2, w1rot, B);
                const float act2 = fmaf(amul, sig2(B), aadd);
                const float i2 = bperm(aj,       act2);
                const float f2 = bperm(aj +  64, act2);
                const float g2 = bperm(aj + 128, act2);
                const float o2 = bperm(aj + 192, act2);
                c2 = fmaf(f2, c2, i2 * g2);
                h2 = o2 * fmaf(2.f, sig2(NT * c2), -1.f);
            }

            // (5) layer-1 update
            c1 = fmaf(f1, c1, i1 * g1);
            h1 = o1 * fmaf(2.f, sig2(NT * c1), -1.f);
            hb1 = rorq<8>(h1);
            Xp = X;
        }
        xq = xn;
    }

    // Epilogue: layer-2 steps T-2 (Xp, h2[T-3]) and T-1 (h1[T-1], h2[T-2]).
#pragma unroll
    for (int e = 0; e < 2; ++e) {
        float B;
        if (e == 0) {
            B = Xp;
        } else {
            f32x2 X2 = {bb1s, 0.f};
            XStep<0>::run(h1, hb1, wxp, X2);
            B = X2.x + X2.y;
        }
        ChainStep<0>::run(h2, w1rot, B);
        const float act2 = fmaf(amul, sig2(B), aadd);
        const float i2 = bperm(aj,       act2);
        const float f2 = bperm(aj +  64, act2);
        const float g2 = bperm(aj + 128, act2);
        const float o2 = bperm(aj + 192, act2);
        c2 = fmaf(f2, c2, i2 * g2);
        h2 = o2 * fmaf(2.f, sig2(NT * c2), -1.f);
    }

    // head: out[b][m] = relu(h2) . Wout[m] + bout[m]
    const float rh = fmaxf(h2, 0.f);
#pragma unroll
    for (int m = 0; m < 5; ++m) {
        float p = rh * Wout[m * 16 + j];
        p += __shfl_xor(p, 1, 16);
        p += __shfl_xor(p, 2, 16);
        p += __shfl_xor(p, 4, 16);
        p += __shfl_xor(p, 8, 16);
        if (lane == m) out[b * 5 + m] = p + bout[m];
    }
}

extern "C" void kernel_launch(void* const* d_in, const int* in_sizes, int n_in,
                              void* d_out, int out_size, void* d_ws, size_t ws_size,
                              hipStream_t stream) {
    const float* x    = (const float*)d_in[0];
    const float* Wih0 = (const float*)d_in[1];
    const float* Whh0 = (const float*)d_in[2];
    const float* bih0 = (const float*)d_in[3];
    const float* bhh0 = (const float*)d_in[4];
    const float* Wih1 = (const float*)d_in[5];
    const float* Whh1 = (const float*)d_in[6];
    const float* bih1 = (const float*)d_in[7];
    const float* bhh1 = (const float*)d_in[8];
    const float* Wout = (const float*)d_in[9];
    const float* bout = (const float*)d_in[10];
    float* out = (float*)d_out;

    const int B = in_sizes[0] / T_LEN;          // 4096
    dim3 grid(B / 4), block(256);               // 1 wave per sequence
    hipLaunchKernelGGL(lstm2_dpp_kernel, grid, block, 0, stream,
                       x, Wih0, Whh0, bih0, bhh0,
                       Wih1, Whh1, bih1, bhh1, Wout, bout, out);
}

// Round 6
// 586.339 us; speedup vs baseline: 1.5445x; 1.5445x over previous
//
#include <hip/hip_runtime.h>

static constexpr int T_LEN = 1024;

typedef _Float16 f16;
typedef f16  f16x4 __attribute__((ext_vector_type(4)));
typedef float f32x4 __attribute__((ext_vector_type(4)));

__device__ __forceinline__ f32x4 mfma16(f16x4 a, f16x4 b, f32x4 c) {
    return __builtin_amdgcn_mfma_f32_16x16x16f16(a, b, c, 0, 0, 0);
}
// 1/(1+2^t): overflow-safe (t->+inf: exp2=inf, rcp->0; t->-inf: ->1)
__device__ __forceinline__ float sig2(float t) {
    return __builtin_amdgcn_rcpf(1.f + __builtin_amdgcn_exp2f(t));
}

// One wave (64 threads) per block, 16 sequences per wave, 256 blocks = 1/CU.
// Fragments (v_mfma_f32_16x16x16f16, classic CDNA layout):
//   A[m][k]: lane = m + 16*(k/4), reg = k%4   (weights, f16, pre-scaled)
//   B[k][n]: lane = n + 16*(k/4), reg = k%4   (H^T: k=hidden, n=seq)
//   D[m][n]: lane = n + 16*(m/4), reg = m%4   (gates: m=gate-row, n=seq)
// B and D share the same lane mapping, so the updated h fragment feeds the
// next step's MFMA directly — no cross-lane data movement per step.
// Gate groups g=0..3 = i,f,g,o (PyTorch order); 4 MFMAs per layer keep
// i/f/g/o colocated per lane-reg for the elementwise LSTM update.
__global__ void __launch_bounds__(64, 1) lstm2_mfma_kernel(
    const float* __restrict__ x,
    const float* __restrict__ Wih0, const float* __restrict__ Whh0,
    const float* __restrict__ bih0, const float* __restrict__ bhh0,
    const float* __restrict__ Wih1, const float* __restrict__ Whh1,
    const float* __restrict__ bih1, const float* __restrict__ bhh1,
    const float* __restrict__ Wout, const float* __restrict__ bout,
    float* __restrict__ out)
{
    const int l   = threadIdx.x & 63;
    const int col = l & 15;            // seq within tile (B/C/D col); A row
    const int q   = l >> 4;            // quad index
    const int seq = blockIdx.x * 16 + col;

    const float L2E = 1.442695041f;
    const float NT  = -2.f * L2E;      // tanh(c) scale

    // ---- constant fragments (weights f16 pre-scaled by -log2e per group;
    //      tanh group g==2 scaled by -2log2e since tanh(v)=2*sig(2v)-1).
    f16x4 Wa0[4], Wax[4], Wa1[4];      // A-frags: Whh0, Wih1, Whh1
    f32x4 cb1[4], wx0[4], cb2[4];      // D-layout consts: bias1, Wih0, bias2
#pragma unroll
    for (int g = 0; g < 4; ++g) {
        const float ns   = (g == 2) ? (-2.f * L2E) : (-L2E);
        const int   arow = g * 16 + col;       // A: row = lane&15
#pragma unroll
        for (int r = 0; r < 4; ++r) {
            Wa0[g][r] = (f16)(ns * Whh0[arow * 16 + q * 4 + r]);
            Wax[g][r] = (f16)(ns * Wih1[arow * 16 + q * 4 + r]);
            Wa1[g][r] = (f16)(ns * Whh1[arow * 16 + q * 4 + r]);
            const int drow = g * 16 + q * 4 + r;  // D: row = 4q+r
            cb1[g][r] = ns * (bih0[drow] + bhh0[drow]);
            wx0[g][r] = ns * Wih0[drow];
            cb2[g][r] = ns * (bih1[drow] + bhh1[drow]);
        }
    }
#pragma unroll
    for (int g = 0; g < 4; ++g)
        asm volatile("" : "+v"(Wa0[g]), "+v"(Wax[g]), "+v"(Wa1[g]),
                          "+v"(cb1[g]), "+v"(wx0[g]), "+v"(cb2[g]));

    f16x4 h1f = {}, h2f = {};          // H^T fragments (f16)
    f32x4 c1 = {0.f, 0.f, 0.f, 0.f}, c2 = {0.f, 0.f, 0.f, 0.f};
    f32x4 h2v = {0.f, 0.f, 0.f, 0.f}; // fp32 h2 (for head)

    const float* xb = x + (size_t)seq * T_LEN;
    float4 xq = *reinterpret_cast<const float4*>(xb);

    for (int tb = 0; tb < T_LEN; tb += 4) {
        float4 xn = xq;
        if (tb + 4 < T_LEN)
            xn = *reinterpret_cast<const float4*>(xb + tb + 4);
#pragma unroll
        for (int u = 0; u < 4; ++u) {
            const float xv = (u==0)?xq.x:(u==1)?xq.y:(u==2)?xq.z:xq.w;

            // ---- layer 1: gates = Whh0·h1 + (Wih0·x + b)   [scaled]
            f32x4 ga[4];
#pragma unroll
            for (int g = 0; g < 4; ++g) {
                f32x4 ci;
#pragma unroll
                for (int r = 0; r < 4; ++r)
                    ci[r] = fmaf(wx0[g][r], xv, cb1[g][r]);
                ga[g] = mfma16(Wa0[g], h1f, ci);
            }
            // activations (scaled preacts: sig = rcp(1+exp2(s)))
            f32x4 sg[4];
#pragma unroll
            for (int g = 0; g < 4; ++g)
#pragma unroll
                for (int r = 0; r < 4; ++r)
                    sg[g][r] = sig2(ga[g][r]);
#pragma unroll
            for (int r = 0; r < 4; ++r)
                sg[2][r] = fmaf(2.f, sg[2][r], -1.f);   // tanh fixup
#pragma unroll
            for (int r = 0; r < 4; ++r) {
                c1[r] = fmaf(sg[1][r], c1[r], sg[0][r] * sg[2][r]);
                const float th = fmaf(2.f, sig2(NT * c1[r]), -1.f);
                h1f[r] = (f16)(sg[3][r] * th);
            }

            // ---- layer 2: gates = Wih1·h1[t] + Whh1·h2[t-1] + b  [scaled]
            f32x4 gb[4];
#pragma unroll
            for (int g = 0; g < 4; ++g)
                gb[g] = mfma16(Wax[g], h1f, mfma16(Wa1[g], h2f, cb2[g]));
#pragma unroll
            for (int g = 0; g < 4; ++g)
#pragma unroll
                for (int r = 0; r < 4; ++r)
                    sg[g][r] = sig2(gb[g][r]);
#pragma unroll
            for (int r = 0; r < 4; ++r)
                sg[2][r] = fmaf(2.f, sg[2][r], -1.f);
#pragma unroll
            for (int r = 0; r < 4; ++r) {
                c2[r] = fmaf(sg[1][r], c2[r], sg[0][r] * sg[2][r]);
                const float th = fmaf(2.f, sig2(NT * c2[r]), -1.f);
                h2v[r] = sg[3][r] * th;
                h2f[r] = (f16)h2v[r];
            }
        }
        xq = xn;
    }

    // ---- head: out[seq][m] = relu(h2) . Wout[m] + bout[m]
    // lane holds h2[u=4q+r][seq=col]; reduce over q via xor-shuffles.
#pragma unroll
    for (int m = 0; m < 5; ++m) {
        float p = 0.f;
#pragma unroll
        for (int r = 0; r < 4; ++r)
            p = fmaf(fmaxf(h2v[r], 0.f), Wout[m * 16 + q * 4 + r], p);
        p += __shfl_xor(p, 16, 64);
        p += __shfl_xor(p, 32, 64);
        if (q == 0) out[seq * 5 + m] = p + bout[m];
    }
}

extern "C" void kernel_launch(void* const* d_in, const int* in_sizes, int n_in,
                              void* d_out, int out_size, void* d_ws, size_t ws_size,
                              hipStream_t stream) {
    const float* x    = (const float*)d_in[0];
    const float* Wih0 = (const float*)d_in[1];
    const float* Whh0 = (const float*)d_in[2];
    const float* bih0 = (const float*)d_in[3];
    const float* bhh0 = (const float*)d_in[4];
    const float* Wih1 = (const float*)d_in[5];
    const float* Whh1 = (const float*)d_in[6];
    const float* bih1 = (const float*)d_in[7];
    const float* bhh1 = (const float*)d_in[8];
    const float* Wout = (const float*)d_in[9];
    const float* bout = (const float*)d_in[10];
    float* out = (float*)d_out;

    const int B = in_sizes[0] / T_LEN;          // 4096
    dim3 grid(B / 16), block(64);               // 1 wave / 16 seqs per block
    hipLaunchKernelGGL(lstm2_mfma_kernel, grid, block, 0, stream,
                       x, Wih0, Whh0, bih0, bhh0,
                       Wih1, Whh1, bih1, bhh1, Wout, bout, out);
}